// Round 22
// baseline (288.726 us; speedup 1.0000x reference)
//
#include <hip/hip_runtime.h>
#include <stdint.h>

typedef float f32x4 __attribute__((ext_vector_type(4)));
typedef __bf16 bf16x8 __attribute__((ext_vector_type(8)));
typedef unsigned short us8 __attribute__((ext_vector_type(8)));
typedef unsigned short us4 __attribute__((ext_vector_type(4)));
typedef unsigned int u32;

#define MFMA16(A, B, C) __builtin_amdgcn_mfma_f32_16x16x32_bf16( \
    __builtin_bit_cast(bf16x8, (A)), __builtin_bit_cast(bf16x8, (B)), (C), 0, 0, 0)

__device__ __forceinline__ unsigned short f2bf(float f) {
  u32 u = __builtin_bit_cast(u32, f);
  u = u + 0x7fffu + ((u >> 16) & 1u);   // RNE
  return (unsigned short)(u >> 16);
}
__device__ __forceinline__ float bf2f(unsigned short b) {
  u32 u = ((u32)b) << 16;
  return __builtin_bit_cast(float, u);
}
// async global->LDS, 16B per lane. LDS dest must be wave-uniform base (HW adds lane*16).
__device__ __forceinline__ void gload16(const void* g, void* lds) {
  __builtin_amdgcn_global_load_lds((const __attribute__((address_space(1))) u32*)g,
                                   (__attribute__((address_space(3))) u32*)lds, 16, 0, 0);
}

// ------ fp32 -> bf16 conversion of x and weights + RoPE sincos table ----------
__global__ __launch_bounds__(256) void convert_all(
    const float* __restrict__ x, const float* __restrict__ wq, const float* __restrict__ wk,
    const float* __restrict__ wv, const float* __restrict__ wo,
    unsigned short* __restrict__ xb, unsigned short* __restrict__ wcat,
    unsigned short* __restrict__ wob, float2* __restrict__ tab) {
  if (blockIdx.x >= 2048) {  // blocks 2048..2111: 131072-entry cos/sin table
    int t0 = ((int)blockIdx.x - 2048) * 2048 + (int)threadIdx.x * 8;
#pragma unroll
    for (int j = 0; j < 8; ++j) {
      int idx = t0 + j;
      int s = idx >> 6, i = idx & 63;
      float ang = (float)s * exp2f(-(float)i * 0.2076205059304703f);
      float sv, cv;
      sincosf(ang, &sv, &cv);
      tab[idx] = make_float2(cv, sv);
    }
    return;
  }
  int tid = blockIdx.x * 256 + threadIdx.x;
  int nth = 2048 * 256;
  const float* srcs[5] = {x, wq, wk, wv, wo};
  unsigned short* dsts[5] = {xb, wcat, wcat + 4194304, wcat + 8388608, wob};
  const int n4s[5] = {2097152, 1048576, 1048576, 1048576, 1048576};
#pragma unroll
  for (int sg = 0; sg < 5; ++sg) {
    const float4* s = (const float4*)srcs[sg];
    us4* d = (us4*)dsts[sg];
    int n4 = n4s[sg];
    for (int i = tid; i < n4; i += nth) {
      float4 v = s[i];
      us4 o;
      o[0] = f2bf(v.x); o[1] = f2bf(v.y); o[2] = f2bf(v.z); o[3] = f2bf(v.w);
      d[i] = o;
    }
  }
}

// ------- 128x192 bf16 GEMM, C = A * B^T (R22: residency-2, 1 barrier/tile) -----
// R20's proven template with BM halved: LDS 2 buf x (A[128][64] 16KB + B[192][64]
// 24KB) = 80KB -> TWO blocks/CU (160KB exactly); acc[3][4] = 48 regs -> ~119
// total < 128 -> 16 waves/CU. Grid 32x32 = 1024 = exact 2 rounds of 2-resident.
// Per-CU LDS traffic unchanged (shared) — this isolates LATENCY-HIDING (m114:
// co-resident block's MFMA covers this block's stalls; R20 showed barriers are
// only ~3%, so lockstep latency is the remaining stall). Same swizzle, coalesced
// line staging, 1-barrier TILE1, VMW(0) ledger (stages into b^1 whose last read
// was 1 barrier ago; reads of b gated by all-waves VMW(0) before the barrier).
// 8 waves 2Mx4N: wave tile 64x48; A = 2 stage-calls, B = 3.
template <int EPI>
__global__ __launch_bounds__(512, 2) void gemmsw(
    const unsigned short* __restrict__ A, const unsigned short* __restrict__ B,
    int nTN, int N,
    float* __restrict__ outF, const float* __restrict__ bias,
    unsigned short* __restrict__ qb, unsigned short* __restrict__ kb,
    unsigned short* __restrict__ vtb, const float* __restrict__ bq,
    const float* __restrict__ bv, const float2* __restrict__ tab) {
  constexpr int KT = 32;  // K=2048 / BK=64
  __shared__ alignas(16) char L[81920];   // 2 x 40960 (A 16KB + B 24KB)
  char* Lp = L;
  int bid = (int)blockIdx.x, nwg = (int)gridDim.x;
  {  // XCD-aware swizzle; grid 1024 % 8 == 0
    int qq = nwg >> 3;
    int xcd = bid & 7, idx = bid >> 3;
    bid = xcd * qq + idx;
  }
  int tm = bid / nTN, tn = bid % nTN;
  int t = (int)threadIdx.x, l = t & 63, w = t >> 6;
  int g = l >> 4, ln = l & 15;
  int wr = w >> 2, wc = w & 3;   // 2M x 4N wave grid; wave tile 64x48
  int lr = l >> 3, lc = l & 7;
  int scol = lc ^ lr;
  const unsigned short* pAs = A + (size_t)(tm * 128 + w * 8 + lr) * 2048 + scol * 8;
  const unsigned short* pBs = B + (size_t)(tn * 192 + w * 8 + lr) * 2048 + scol * 8;

  f32x4 acc[3][4] = {};
  us8 af[4][2], bf3[3][2];

#define FENCE asm volatile("" ::: "memory")
#define BAR do { FENCE; __builtin_amdgcn_s_barrier(); FENCE; } while (0)
#define VMW_(n) asm volatile("s_waitcnt vmcnt(" #n ")" ::: "memory")
#define VMW(n) VMW_(n)
#define STA(i, kt, bufsel) do { if ((kt) < KT)                                \
    gload16(pAs + (size_t)(i) * 131072 + (size_t)(kt) * 64,                   \
            Lp + (bufsel) * 40960 + (i) * 8192 + w * 1024); } while (0)
#define STB(i, kt, bufsel) do { if ((kt) < KT)                                \
    gload16(pBs + (size_t)(i) * 131072 + (size_t)(kt) * 64,                   \
            Lp + (bufsel) * 40960 + 16384 + (i) * 8192 + w * 1024); } while (0)
#define RD_AALL(bufsel) do {                                                  \
    _Pragma("unroll") for (int mf = 0; mf < 4; ++mf)                          \
    _Pragma("unroll") for (int kc = 0; kc < 2; ++kc)                          \
      af[mf][kc] = *(const us8*)(Lp + (bufsel) * 40960 +                      \
          (wr * 64 + mf * 16 + ln) * 128 +                                    \
          ((kc * 64 + g * 16) ^ ((ln & 7) << 4)));                            \
  } while (0)
#define RD_BALL(bufsel) do {                                                  \
    _Pragma("unroll") for (int nh = 0; nh < 3; ++nh)                          \
    _Pragma("unroll") for (int kc = 0; kc < 2; ++kc)                          \
      bf3[nh][kc] = *(const us8*)(Lp + (bufsel) * 40960 + 16384 +             \
          (nh * 64 + wc * 16 + ln) * 128 +                                    \
          ((kc * 64 + g * 16) ^ ((ln & 7) << 4)));                            \
  } while (0)
#define MMALL() do {                                                          \
    __builtin_amdgcn_s_setprio(1);                                            \
    _Pragma("unroll") for (int nh = 0; nh < 3; ++nh)                          \
    _Pragma("unroll") for (int kc = 0; kc < 2; ++kc)                          \
    _Pragma("unroll") for (int mf = 0; mf < 4; ++mf)                          \
      acc[nh][mf] = MFMA16(af[mf][kc], bf3[nh][kc], acc[nh][mf]);             \
    __builtin_amdgcn_s_setprio(0);                                            \
  } while (0)
#define TILE1(kt, b) do {                                                     \
  STA(0, (kt) + 1, (b) ^ 1); STA(1, (kt) + 1, (b) ^ 1);                       \
  STB(0, (kt) + 1, (b) ^ 1); STB(1, (kt) + 1, (b) ^ 1);                       \
  STB(2, (kt) + 1, (b) ^ 1);                                                  \
  RD_AALL(b); RD_BALL(b);                                                     \
  MMALL();                                                                    \
  VMW(0); BAR;                                                                \
} while (0)

  // prologue: tile0 -> buf0, drain, barrier
  STA(0, 0, 0); STA(1, 0, 0);
  STB(0, 0, 0); STB(1, 0, 0); STB(2, 0, 0);
  VMW(0); BAR;

#pragma unroll 1
  for (int kt = 0; kt < 32; kt += 2) {
    TILE1(kt, 0);
    TILE1(kt + 1, 1);
  }

#undef TILE1
#undef MMALL
#undef RD_BALL
#undef RD_AALL
#undef STB
#undef STA
#undef VMW
#undef VMW_
#undef BAR
#undef FENCE

  if (EPI == 1) {
#pragma unroll
    for (int nh = 0; nh < 3; ++nh)
#pragma unroll
    for (int mf = 0; mf < 4; ++mf) {
      int n = tn * 192 + nh * 64 + wc * 16 + ln;
      float bz = bias[n];
      int m0 = tm * 128 + wr * 64 + mf * 16 + g * 4;
#pragma unroll
      for (int r = 0; r < 4; ++r)
        outF[(size_t)(m0 + r) * N + n] = acc[nh][mf][r] + bz;
    }
  } else {
#pragma unroll
    for (int nh = 0; nh < 3; ++nh)
#pragma unroll
    for (int mf = 0; mf < 4; ++mf) {
      int n6 = tn * 192 + nh * 64 + wc * 16 + ln;
      int sel = n6 >> 11, d = n6 & 2047, h = d >> 7, hd = d & 127;
      int m0 = tm * 128 + wr * 64 + mf * 16 + g * 4;
      int b = m0 >> 11, s0 = m0 & 2047;
      if (sel == 2) {  // v -> transposed [bh][hd][S]
        float badd = bv[d];
        us4 pk;
#pragma unroll
        for (int r = 0; r < 4; ++r) pk[r] = f2bf(acc[nh][mf][r] + badd);
        *(us4*)&vtb[((size_t)(b * 16 + h) * 128 + hd) * 2048 + s0] = pk;
      } else {  // q/k -> [bh][S][hd], RoPE fused (pair = adjacent lanes ln^1)
        unsigned short* dst = sel ? kb : qb;
        float badd = sel ? 0.f : bq[d];
        int odd = hd & 1;
#pragma unroll
        for (int r = 0; r < 4; ++r) {
          float val = acc[nh][mf][r] + badd;
          float pv = __shfl_xor(val, 1);  // partner hd (other half of pair)
          float2 cs = tab[((s0 + r) << 6) | (hd >> 1)];
          float rot = odd ? (val * cs.x + pv * cs.y) : (val * cs.x - pv * cs.y);
          dst[((size_t)(b * 16 + h) * 2048 + (s0 + r)) * 128 + hd] = f2bf(rot);
        }
      }
    }
  }
}

// ------- out-proj 128x256 BK=64 engine (R21 1-barrier, verified) ---------------
__global__ __launch_bounds__(512, 2) void gemmo(
    const unsigned short* __restrict__ A, const unsigned short* __restrict__ B,
    int nTN, int N,
    float* __restrict__ outF, const float* __restrict__ bias) {
  constexpr int KT = 32;
  __shared__ alignas(16) char L[147456];  // 3 x 49152
  char* Lp = L;
  int bid = (int)blockIdx.x, nwg = (int)gridDim.x;
  {
    int qq = nwg >> 3;
    int xcd = bid & 7, idx = bid >> 3;
    bid = xcd * qq + idx;
  }
  int tm = bid / nTN, tn = bid % nTN;
  int t = (int)threadIdx.x, l = t & 63, w = t >> 6;
  int g = l >> 4, ln = l & 15;
  int wr = w >> 2, wc = w & 3;
  int lr = l >> 3, lc = l & 7;
  int scol = lc ^ lr;
  const unsigned short* pAs = A + (size_t)(tm * 128 + w * 8 + lr) * 2048 + scol * 8;
  const unsigned short* pBs = B + (size_t)(tn * 256 + w * 8 + lr) * 2048 + scol * 8;

  f32x4 acc[4][4] = {};
  us8 af[4][2], bfp[2][2];

#define FENCE asm volatile("" ::: "memory")
#define BAR do { FENCE; __builtin_amdgcn_s_barrier(); FENCE; } while (0)
#define VMW_(n) asm volatile("s_waitcnt vmcnt(" #n ")" ::: "memory")
#define VMW(n) VMW_(n)
#define OSTA(i, kt, bufsel) do { if ((kt) < KT)                               \
    gload16(pAs + (size_t)(i) * 131072 + (size_t)(kt) * 64,                   \
            Lp + (bufsel) * 49152 + (i) * 8192 + w * 1024); } while (0)
#define OSTB(i, kt, bufsel) do { if ((kt) < KT)                               \
    gload16(pBs + (size_t)(i) * 131072 + (size_t)(kt) * 64,                   \
            Lp + (bufsel) * 49152 + 16384 + (i) * 8192 + w * 1024); } while (0)
#define ORD_A(bufsel) do {                                                    \
    _Pragma("unroll") for (int mf = 0; mf < 4; ++mf)                          \
    _Pragma("unroll") for (int kc = 0; kc < 2; ++kc)                          \
      af[mf][kc] = *(const us8*)(Lp + (bufsel) * 49152 +                      \
          (wr * 64 + mf * 16 + ln) * 128 +                                    \
          ((kc * 64 + g * 16) ^ ((ln & 7) << 4)));                            \
  } while (0)
#define ORD_B2(ph, bufsel) do {                                               \
    _Pragma("unroll") for (int np = 0; np < 2; ++np)                          \
    _Pragma("unroll") for (int kc = 0; kc < 2; ++kc)                          \
      bfp[np][kc] = *(const us8*)(Lp + (bufsel) * 49152 + 16384 +             \
          (((ph) * 2 + np) * 64 + wc * 16 + ln) * 128 +                       \
          ((kc * 64 + g * 16) ^ ((ln & 7) << 4)));                            \
  } while (0)
#define OMM(ph) do {                                                          \
    __builtin_amdgcn_s_setprio(1);                                            \
    _Pragma("unroll") for (int np = 0; np < 2; ++np)                          \
    _Pragma("unroll") for (int kc = 0; kc < 2; ++kc)                          \
    _Pragma("unroll") for (int mf = 0; mf < 4; ++mf)                          \
      acc[(ph) * 2 + np][mf] = MFMA16(af[mf][kc], bfp[np][kc],                \
                                      acc[(ph) * 2 + np][mf]);                \
    __builtin_amdgcn_s_setprio(0);                                            \
  } while (0)
#define OTILE1(kt, bc, bs, VMB) do {                                          \
  OSTA(0, (kt) + 2, bs); OSTA(1, (kt) + 2, bs);                               \
  OSTB(0, (kt) + 2, bs); OSTB(1, (kt) + 2, bs);                               \
  OSTB(2, (kt) + 2, bs); OSTB(3, (kt) + 2, bs);                               \
  ORD_A(bc); ORD_B2(0, bc);                                                   \
  OMM(0);                                                                     \
  ORD_B2(1, bc);                                                              \
  OMM(1);                                                                     \
  VMW(VMB); BAR;                                                              \
} while (0)

  OSTA(0, 0, 0); OSTA(1, 0, 0); OSTB(0, 0, 0); OSTB(1, 0, 0);
  OSTB(2, 0, 0); OSTB(3, 0, 0);
  OSTA(0, 1, 1); OSTA(1, 1, 1); OSTB(0, 1, 1); OSTB(1, 1, 1);
  OSTB(2, 1, 1); OSTB(3, 1, 1);
  VMW(6); BAR;

#pragma unroll 1
  for (int j = 0; j < 10; ++j) {
    int k0 = j * 3;
    OTILE1(k0 + 0, 0, 2, 6);
    OTILE1(k0 + 1, 1, 0, 6);
    OTILE1(k0 + 2, 2, 1, 6);
  }
  OTILE1(30, 0, 2, 0);   // stages t32 guarded out; VMW(0) confirms tile 31
  OTILE1(31, 1, 0, 0);   // nothing outstanding

#undef OTILE1
#undef OMM
#undef ORD_B2
#undef ORD_A
#undef OSTB
#undef OSTA
#undef VMW
#undef VMW_
#undef BAR
#undef FENCE

#pragma unroll
  for (int nh = 0; nh < 4; ++nh)
#pragma unroll
  for (int mf = 0; mf < 4; ++mf) {
    int n = tn * 256 + nh * 64 + wc * 16 + ln;
    float bz = bias[n];
    int m0 = tm * 128 + wr * 64 + mf * 16 + g * 4;
#pragma unroll
    for (int r = 0; r < 4; ++r)
      outF[(size_t)(m0 + r) * N + n] = acc[nh][mf][r] + bz;
  }
}

// ---------------- causal flash attention (R15-verified: merged halves + dbuf) --
__global__ __launch_bounds__(512) void attn_k(
    const unsigned short* __restrict__ qg, const unsigned short* __restrict__ kg,
    const unsigned short* __restrict__ vtg, unsigned short* __restrict__ ab) {
  __shared__ alignas(16) unsigned short Kl[2][64 * 128];   // [buf][key][hd], swz
  __shared__ alignas(16) unsigned short Vl[2][128 * 64];   // [buf][hd][key], swz
  __shared__ alignas(16) unsigned short Pl[8][16 * 72];    // per wave [qrow][key]
  int bh = (int)blockIdx.x & 31;
  int pr = (int)blockIdx.x >> 5;     // 0..7
  int t = (int)threadIdx.x, l = t & 63, w = t >> 6;
  int g = l >> 4, ln = l & 15;
  int b = bh >> 4, h = bh & 15;
  const size_t bq0 = (size_t)bh * 2048 * 128;

  const int qbA = pr * 128, qbB = (15 - pr) * 128;
  const int qrowA = qbA + w * 16 + ln, qrowB = qbB + w * 16 + ln;
  us8 qfA[4], qfB[4];
#pragma unroll
  for (int kf = 0; kf < 4; ++kf) {
    qfA[kf] = *(const us8*)&qg[bq0 + (size_t)qrowA * 128 + kf * 32 + g * 8];
    qfB[kf] = *(const us8*)&qg[bq0 + (size_t)qrowB * 128 + kf * 32 + g * 8];
  }
  f32x4 oA[8] = {}, oB[8] = {};
  float mA = -1e30f, lA = 0.f, mB = -1e30f, lB = 0.f;
  const int nktA = (qbA >> 6) + 2;   // 2pr+2
  const int nkt  = (qbB >> 6) + 2;   // 32-2pr

#define STAGEKV(kt1, bsel) do {                                               \
    _Pragma("unroll") for (int i = 0; i < 2; ++i) {                           \
      int fb = i * 8192 + w * 1024;                                           \
      int flat = fb + l * 16;                                                 \
      int row = flat >> 8, colb = flat & 255;                                 \
      int sc = colb ^ ((row & 7) << 4);                                       \
      gload16(kg + (bq0 + (size_t)((kt1) * 64 + row) * 128 + (sc >> 1)),      \
              (char*)Kl + (bsel) * 16384 + fb);                               \
      int rv = flat >> 7, cv2 = flat & 127;                                   \
      int scv = cv2 ^ ((rv & 7) << 4);                                        \
      gload16(vtg + (bq0 + (size_t)rv * 2048 + (kt1) * 64 + (scv >> 1)),      \
              (char*)Vl + (bsel) * 16384 + fb);                               \
    }                                                                         \
  } while (0)

#define COMPUTE(qf, o, mrow, lrow, qrow, kt, bo) do {                         \
    f32x4 st[4];                                                              \
    _Pragma("unroll") for (int kfr = 0; kfr < 4; ++kfr) {                     \
      f32x4 acc = {};                                                         \
      int row = kfr * 16 + ln;                                                \
      int swz = (row & 7) << 4;                                               \
      _Pragma("unroll") for (int kf = 0; kf < 4; ++kf) {                      \
        us8 kfrag = *(const us8*)((const char*)Kl + (bo) + row * 256 +        \
                                  ((kf * 64 + g * 16) ^ swz));                \
        acc = MFMA16(kfrag, qf[kf], acc);                                     \
      }                                                                       \
      st[kfr] = acc;                                                          \
    }                                                                         \
    float pmax = -1e30f;                                                      \
    _Pragma("unroll") for (int kfr = 0; kfr < 4; ++kfr)                       \
    _Pragma("unroll") for (int r = 0; r < 4; ++r) {                           \
      int key = (kt) * 64 + kfr * 16 + g * 4 + r;                             \
      float sv = key <= (qrow) ? st[kfr][r] * 0.08838834764831845f : -1e30f;  \
      st[kfr][r] = sv;                                                        \
      pmax = fmaxf(pmax, sv);                                                 \
    }                                                                         \
    pmax = fmaxf(pmax, __shfl_xor(pmax, 16));                                 \
    pmax = fmaxf(pmax, __shfl_xor(pmax, 32));                                 \
    if (__ballot(pmax > (mrow) + 8.f)) {                                      \
      float mnew = pmax > (mrow) + 8.f ? pmax : (mrow);                       \
      float corr = exp2f(((mrow) - mnew) * 1.44269504f);                      \
      (mrow) = mnew;                                                          \
      (lrow) *= corr;                                                         \
      _Pragma("unroll") for (int r = 0; r < 4; ++r) {                         \
        float cr = __shfl(corr, g * 4 + r);                                   \
        _Pragma("unroll") for (int nf = 0; nf < 8; ++nf) o[nf][r] *= cr;      \
      }                                                                       \
    }                                                                         \
    float lsum = 0.f;                                                         \
    _Pragma("unroll") for (int kfr = 0; kfr < 4; ++kfr) {                     \
      us4 pk;                                                                 \
      _Pragma("unroll") for (int r = 0; r < 4; ++r) {                         \
        float p = exp2f((st[kfr][r] - (mrow)) * 1.44269504f);                 \
        lsum += p;                                                            \
        pk[r] = f2bf(p);                                                      \
      }                                                                       \
      *(us4*)&Pl[w][ln * 72 + kfr * 16 + g * 4] = pk;                         \
    }                                                                         \
    lsum += __shfl_xor(lsum, 16);                                             \
    lsum += __shfl_xor(lsum, 32);                                             \
    (lrow) += lsum;                                                           \
    _Pragma("unroll") for (int kf2 = 0; kf2 < 2; ++kf2) {                     \
      us8 pa = *(const us8*)&Pl[w][ln * 72 + kf2 * 32 + g * 8];               \
      _Pragma("unroll") for (int nf = 0; nf < 8; ++nf) {                      \
        int row = nf * 16 + ln;                                               \
        us8 vb = *(const us8*)((const char*)Vl + (bo) + row * 128 +           \
                               ((kf2 * 64 + g * 16) ^ ((row & 7) << 4)));     \
        o[nf] = MFMA16(pa, vb, o[nf]);                                        \
      }                                                                       \
    }                                                                         \
  } while (0)

  STAGEKV(0, 0);
#pragma unroll 1
  for (int kt = 0; kt < nkt; ++kt) {
    __syncthreads();
    if (kt + 1 < nkt) STAGEKV(kt + 1, (kt + 1) & 1);
    int bo = (kt & 1) * 16384;
    COMPUTE(qfB, oB, mB, lB, qrowB, kt, bo);
    if (kt < nktA) COMPUTE(qfA, oA, mA, lA, qrowA, kt, bo);
  }
#undef COMPUTE
#undef STAGEKV

  {
    float invl = 1.f / lB;
#pragma unroll
    for (int r = 0; r < 4; ++r) {
      float ir = __shfl(invl, g * 4 + r);
      int srow = qbB + w * 16 + g * 4 + r;
      size_t base = ((size_t)b * 2048 + srow) * 2048 + h * 128 + ln;
#pragma unroll
      for (int nf = 0; nf < 8; ++nf) ab[base + (size_t)nf * 16] = f2bf(oB[nf][r] * ir);
    }
  }
  {
    float invl = 1.f / lA;
#pragma unroll
    for (int r = 0; r < 4; ++r) {
      float ir = __shfl(invl, g * 4 + r);
      int srow = qbA + w * 16 + g * 4 + r;
      size_t base = ((size_t)b * 2048 + srow) * 2048 + h * 128 + ln;
#pragma unroll
      for (int nf = 0; nf < 8; ++nf) ab[base + (size_t)nf * 16] = f2bf(oA[nf][r] * ir);
    }
  }
}

extern "C" void kernel_launch(void* const* d_in, const int* in_sizes, int n_in,
                              void* d_out, int out_size, void* d_ws, size_t ws_size,
                              hipStream_t stream) {
  const float* x  = (const float*)d_in[0];
  const float* Wq = (const float*)d_in[1];
  const float* bq = (const float*)d_in[2];
  const float* Wk = (const float*)d_in[3];
  const float* Wv = (const float*)d_in[4];
  const float* bv = (const float*)d_in[5];
  const float* Wo = (const float*)d_in[6];
  const float* bo = (const float*)d_in[7];
  float* out = (float*)d_out;

  unsigned short* ws = (unsigned short*)d_ws;
  unsigned short* xb   = ws;                // 8388608 elems (x bf16; later reused as attn out)
  unsigned short* wcat = xb + 8388608;      // 12582912 (Wq|Wk|Wv rows, [6144][2048])
  unsigned short* wob  = wcat + 12582912;   // 4194304
  unsigned short* qb   = wob + 4194304;     // 8388608  [32][2048][128]
  unsigned short* kb   = qb + 8388608;      // 8388608
  unsigned short* vtb  = kb + 8388608;      // 8388608  [32][128][2048] (transposed)
  float2* tab = (float2*)(vtb + 8388608);   // 131072 float2 (1MB) RoPE table

  convert_all<<<2112, 256, 0, stream>>>(x, Wq, Wk, Wv, Wo, xb, wcat, wob, tab);
  gemmsw<0><<<1024, 512, 0, stream>>>(xb, wcat, 32, 6144,
                                      nullptr, nullptr, qb, kb, vtb, bq, bv, tab);
  attn_k<<<256, 512, 0, stream>>>(qb, kb, vtb, xb /* a_buf alias */);
  gemmo<<<256, 512, 0, stream>>>(xb, wob, 8, 2048, out, bo);
}

// Round 23
// 248.186 us; speedup vs baseline: 1.1633x; 1.1633x over previous
//
#include <hip/hip_runtime.h>
#include <stdint.h>

typedef float f32x4 __attribute__((ext_vector_type(4)));
typedef __bf16 bf16x8 __attribute__((ext_vector_type(8)));
typedef unsigned short us8 __attribute__((ext_vector_type(8)));
typedef unsigned short us4 __attribute__((ext_vector_type(4)));
typedef unsigned int u32;

#define MFMA16(A, B, C) __builtin_amdgcn_mfma_f32_16x16x32_bf16( \
    __builtin_bit_cast(bf16x8, (A)), __builtin_bit_cast(bf16x8, (B)), (C), 0, 0, 0)

__device__ __forceinline__ unsigned short f2bf(float f) {
  u32 u = __builtin_bit_cast(u32, f);
  u = u + 0x7fffu + ((u >> 16) & 1u);   // RNE
  return (unsigned short)(u >> 16);
}
__device__ __forceinline__ float bf2f(unsigned short b) {
  u32 u = ((u32)b) << 16;
  return __builtin_bit_cast(float, u);
}
// async global->LDS, 16B per lane. LDS dest must be wave-uniform base (HW adds lane*16).
__device__ __forceinline__ void gload16(const void* g, void* lds) {
  __builtin_amdgcn_global_load_lds((const __attribute__((address_space(1))) u32*)g,
                                   (__attribute__((address_space(3))) u32*)lds, 16, 0, 0);
}

// ------ fp32 -> bf16 conversion of x and weights + RoPE sincos table ----------
__global__ __launch_bounds__(256) void convert_all(
    const float* __restrict__ x, const float* __restrict__ wq, const float* __restrict__ wk,
    const float* __restrict__ wv, const float* __restrict__ wo,
    unsigned short* __restrict__ xb, unsigned short* __restrict__ wcat,
    unsigned short* __restrict__ wob, float2* __restrict__ tab) {
  if (blockIdx.x >= 2048) {  // blocks 2048..2111: 131072-entry cos/sin table
    int t0 = ((int)blockIdx.x - 2048) * 2048 + (int)threadIdx.x * 8;
#pragma unroll
    for (int j = 0; j < 8; ++j) {
      int idx = t0 + j;
      int s = idx >> 6, i = idx & 63;
      float ang = (float)s * exp2f(-(float)i * 0.2076205059304703f);
      float sv, cv;
      sincosf(ang, &sv, &cv);
      tab[idx] = make_float2(cv, sv);
    }
    return;
  }
  int tid = blockIdx.x * 256 + threadIdx.x;
  int nth = 2048 * 256;
  const float* srcs[5] = {x, wq, wk, wv, wo};
  unsigned short* dsts[5] = {xb, wcat, wcat + 4194304, wcat + 8388608, wob};
  const int n4s[5] = {2097152, 1048576, 1048576, 1048576, 1048576};
#pragma unroll
  for (int sg = 0; sg < 5; ++sg) {
    const float4* s = (const float4*)srcs[sg];
    us4* d = (us4*)dsts[sg];
    int n4 = n4s[sg];
    for (int i = tid; i < n4; i += nth) {
      float4 v = s[i];
      us4 o;
      o[0] = f2bf(v.x); o[1] = f2bf(v.y); o[2] = f2bf(v.z); o[3] = f2bf(v.w);
      d[i] = o;
    }
  }
}

// ------- 256x192 bf16 GEMM, C = A * B^T (R20: ONE barrier per K-tile; 110us) ---
template <int EPI>
__global__ __launch_bounds__(512, 2) void gemmsw(
    const unsigned short* __restrict__ A, const unsigned short* __restrict__ B,
    int nTN, int N,
    float* __restrict__ outF, const float* __restrict__ bias,
    unsigned short* __restrict__ qb, unsigned short* __restrict__ kb,
    unsigned short* __restrict__ vtb, const float* __restrict__ bq,
    const float* __restrict__ bv, const float2* __restrict__ tab) {
  constexpr int KT = 32;  // K=2048 / BK=64
  __shared__ alignas(16) char L[114688];
  char* Lp = L;
  int bid = (int)blockIdx.x, nwg = (int)gridDim.x;
  {  // XCD-aware swizzle; grid 512 % 8 == 0
    int qq = nwg >> 3;
    int xcd = bid & 7, idx = bid >> 3;
    bid = xcd * qq + idx;
  }
  int tm = bid / nTN, tn = bid % nTN;
  int t = (int)threadIdx.x, l = t & 63, w = t >> 6;
  int g = l >> 4, ln = l & 15;
  int wr = w >> 2, wc = w & 3;   // 2M x 4N wave grid
  int lr = l >> 3, lc = l & 7;
  int scol = lc ^ lr;
  const unsigned short* pAs = A + (size_t)(tm * 256 + w * 8 + lr) * 2048 + scol * 8;
  const unsigned short* pBs = B + (size_t)(tn * 192 + w * 8 + lr) * 2048 + scol * 8;

  f32x4 acc[2][3][4] = {};
  us8 af[2][4][2], bf3[3][2];

#define FENCE asm volatile("" ::: "memory")
#define BAR do { FENCE; __builtin_amdgcn_s_barrier(); FENCE; } while (0)
#define VMW_(n) asm volatile("s_waitcnt vmcnt(" #n ")" ::: "memory")
#define VMW(n) VMW_(n)
#define STA(i, kt, bufsel) do { if ((kt) < KT)                                \
    gload16(pAs + (size_t)(i) * 131072 + (size_t)(kt) * 64,                   \
            Lp + (bufsel) * 57344 + (i) * 8192 + w * 1024); } while (0)
#define STB(i, kt, bufsel) do { if ((kt) < KT)                                \
    gload16(pBs + (size_t)(i) * 131072 + (size_t)(kt) * 64,                   \
            Lp + (bufsel) * 57344 + 32768 + (i) * 8192 + w * 1024); } while (0)
#define RD_AALL(bufsel) do {                                                  \
    _Pragma("unroll") for (int mh = 0; mh < 2; ++mh)                          \
    _Pragma("unroll") for (int mf = 0; mf < 4; ++mf)                          \
    _Pragma("unroll") for (int kc = 0; kc < 2; ++kc)                          \
      af[mh][mf][kc] = *(const us8*)(Lp + (bufsel) * 57344 +                  \
          (wr * 128 + mh * 64 + mf * 16 + ln) * 128 +                         \
          ((kc * 64 + g * 16) ^ ((ln & 7) << 4)));                            \
  } while (0)
#define RD_BALL(bufsel) do {                                                  \
    _Pragma("unroll") for (int nh = 0; nh < 3; ++nh)                          \
    _Pragma("unroll") for (int kc = 0; kc < 2; ++kc)                          \
      bf3[nh][kc] = *(const us8*)(Lp + (bufsel) * 57344 + 32768 +             \
          (nh * 64 + wc * 16 + ln) * 128 +                                    \
          ((kc * 64 + g * 16) ^ ((ln & 7) << 4)));                            \
  } while (0)
#define MMALL() do {                                                          \
    __builtin_amdgcn_s_setprio(1);                                            \
    _Pragma("unroll") for (int nh = 0; nh < 3; ++nh)                          \
    _Pragma("unroll") for (int kc = 0; kc < 2; ++kc)                          \
    _Pragma("unroll") for (int mh = 0; mh < 2; ++mh)                          \
    _Pragma("unroll") for (int mf = 0; mf < 4; ++mf)                          \
      acc[mh][nh][mf] = MFMA16(af[mh][mf][kc], bf3[nh][kc], acc[mh][nh][mf]); \
    __builtin_amdgcn_s_setprio(0);                                            \
  } while (0)
#define TILE1(kt, b) do {                                                     \
  STA(0, (kt) + 1, (b) ^ 1); STA(1, (kt) + 1, (b) ^ 1);                       \
  STA(2, (kt) + 1, (b) ^ 1); STA(3, (kt) + 1, (b) ^ 1);                       \
  STB(0, (kt) + 1, (b) ^ 1); STB(1, (kt) + 1, (b) ^ 1);                       \
  STB(2, (kt) + 1, (b) ^ 1);                                                  \
  RD_AALL(b); RD_BALL(b);                                                     \
  MMALL();                                                                    \
  VMW(0); BAR;                                                                \
} while (0)

  // prologue: tile0 -> buf0, drain, barrier
  STA(0, 0, 0); STA(1, 0, 0); STA(2, 0, 0); STA(3, 0, 0);
  STB(0, 0, 0); STB(1, 0, 0); STB(2, 0, 0);
  VMW(0); BAR;

#pragma unroll 1
  for (int kt = 0; kt < 32; kt += 2) {
    TILE1(kt, 0);
    TILE1(kt + 1, 1);
  }

#undef TILE1
#undef MMALL
#undef RD_BALL
#undef RD_AALL
#undef STB
#undef STA
#undef VMW
#undef VMW_
#undef BAR
#undef FENCE

  if (EPI == 1) {
#pragma unroll
    for (int mh = 0; mh < 2; ++mh)
#pragma unroll
    for (int nh = 0; nh < 3; ++nh)
#pragma unroll
    for (int mf = 0; mf < 4; ++mf) {
      int n = tn * 192 + nh * 64 + wc * 16 + ln;
      float bz = bias[n];
      int m0 = tm * 256 + wr * 128 + mh * 64 + mf * 16 + g * 4;
#pragma unroll
      for (int r = 0; r < 4; ++r)
        outF[(size_t)(m0 + r) * N + n] = acc[mh][nh][mf][r] + bz;
    }
  } else {
#pragma unroll
    for (int mh = 0; mh < 2; ++mh)
#pragma unroll
    for (int nh = 0; nh < 3; ++nh)
#pragma unroll
    for (int mf = 0; mf < 4; ++mf) {
      int n6 = tn * 192 + nh * 64 + wc * 16 + ln;
      int sel = n6 >> 11, d = n6 & 2047, h = d >> 7, hd = d & 127;
      int m0 = tm * 256 + wr * 128 + mh * 64 + mf * 16 + g * 4;
      int b = m0 >> 11, s0 = m0 & 2047;
      if (sel == 2) {  // v -> transposed [bh][hd][S]
        float badd = bv[d];
        us4 pk;
#pragma unroll
        for (int r = 0; r < 4; ++r) pk[r] = f2bf(acc[mh][nh][mf][r] + badd);
        *(us4*)&vtb[((size_t)(b * 16 + h) * 128 + hd) * 2048 + s0] = pk;
      } else {  // q/k -> [bh][S][hd], RoPE fused (pair = adjacent lanes ln^1)
        unsigned short* dst = sel ? kb : qb;
        float badd = sel ? 0.f : bq[d];
        int odd = hd & 1;
#pragma unroll
        for (int r = 0; r < 4; ++r) {
          float val = acc[mh][nh][mf][r] + badd;
          float pv = __shfl_xor(val, 1);  // partner hd (other half of pair)
          float2 cs = tab[((s0 + r) << 6) | (hd >> 1)];
          float rot = odd ? (val * cs.x + pv * cs.y) : (val * cs.x - pv * cs.y);
          dst[((size_t)(b * 16 + h) * 2048 + (s0 + r)) * 128 + hd] = f2bf(rot);
        }
      }
    }
  }
}

// ------- out-proj 128x256 BK=64 engine (R21 1-barrier, verified) ---------------
__global__ __launch_bounds__(512, 2) void gemmo(
    const unsigned short* __restrict__ A, const unsigned short* __restrict__ B,
    int nTN, int N,
    float* __restrict__ outF, const float* __restrict__ bias) {
  constexpr int KT = 32;
  __shared__ alignas(16) char L[147456];  // 3 x 49152
  char* Lp = L;
  int bid = (int)blockIdx.x, nwg = (int)gridDim.x;
  {
    int qq = nwg >> 3;
    int xcd = bid & 7, idx = bid >> 3;
    bid = xcd * qq + idx;
  }
  int tm = bid / nTN, tn = bid % nTN;
  int t = (int)threadIdx.x, l = t & 63, w = t >> 6;
  int g = l >> 4, ln = l & 15;
  int wr = w >> 2, wc = w & 3;
  int lr = l >> 3, lc = l & 7;
  int scol = lc ^ lr;
  const unsigned short* pAs = A + (size_t)(tm * 128 + w * 8 + lr) * 2048 + scol * 8;
  const unsigned short* pBs = B + (size_t)(tn * 256 + w * 8 + lr) * 2048 + scol * 8;

  f32x4 acc[4][4] = {};
  us8 af[4][2], bfp[2][2];

#define FENCE asm volatile("" ::: "memory")
#define BAR do { FENCE; __builtin_amdgcn_s_barrier(); FENCE; } while (0)
#define VMW_(n) asm volatile("s_waitcnt vmcnt(" #n ")" ::: "memory")
#define VMW(n) VMW_(n)
#define OSTA(i, kt, bufsel) do { if ((kt) < KT)                               \
    gload16(pAs + (size_t)(i) * 131072 + (size_t)(kt) * 64,                   \
            Lp + (bufsel) * 49152 + (i) * 8192 + w * 1024); } while (0)
#define OSTB(i, kt, bufsel) do { if ((kt) < KT)                               \
    gload16(pBs + (size_t)(i) * 131072 + (size_t)(kt) * 64,                   \
            Lp + (bufsel) * 49152 + 16384 + (i) * 8192 + w * 1024); } while (0)
#define ORD_A(bufsel) do {                                                    \
    _Pragma("unroll") for (int mf = 0; mf < 4; ++mf)                          \
    _Pragma("unroll") for (int kc = 0; kc < 2; ++kc)                          \
      af[mf][kc] = *(const us8*)(Lp + (bufsel) * 49152 +                      \
          (wr * 64 + mf * 16 + ln) * 128 +                                    \
          ((kc * 64 + g * 16) ^ ((ln & 7) << 4)));                            \
  } while (0)
#define ORD_B2(ph, bufsel) do {                                               \
    _Pragma("unroll") for (int np = 0; np < 2; ++np)                          \
    _Pragma("unroll") for (int kc = 0; kc < 2; ++kc)                          \
      bfp[np][kc] = *(const us8*)(Lp + (bufsel) * 49152 + 16384 +             \
          (((ph) * 2 + np) * 64 + wc * 16 + ln) * 128 +                       \
          ((kc * 64 + g * 16) ^ ((ln & 7) << 4)));                            \
  } while (0)
#define OMM(ph) do {                                                          \
    __builtin_amdgcn_s_setprio(1);                                            \
    _Pragma("unroll") for (int np = 0; np < 2; ++np)                          \
    _Pragma("unroll") for (int kc = 0; kc < 2; ++kc)                          \
    _Pragma("unroll") for (int mf = 0; mf < 4; ++mf)                          \
      acc[(ph) * 2 + np][mf] = MFMA16(af[mf][kc], bfp[np][kc],                \
                                      acc[(ph) * 2 + np][mf]);                \
    __builtin_amdgcn_s_setprio(0);                                            \
  } while (0)
#define OTILE1(kt, bc, bs, VMB) do {                                          \
  OSTA(0, (kt) + 2, bs); OSTA(1, (kt) + 2, bs);                               \
  OSTB(0, (kt) + 2, bs); OSTB(1, (kt) + 2, bs);                               \
  OSTB(2, (kt) + 2, bs); OSTB(3, (kt) + 2, bs);                               \
  ORD_A(bc); ORD_B2(0, bc);                                                   \
  OMM(0);                                                                     \
  ORD_B2(1, bc);                                                              \
  OMM(1);                                                                     \
  VMW(VMB); BAR;                                                              \
} while (0)

  OSTA(0, 0, 0); OSTA(1, 0, 0); OSTB(0, 0, 0); OSTB(1, 0, 0);
  OSTB(2, 0, 0); OSTB(3, 0, 0);
  OSTA(0, 1, 1); OSTA(1, 1, 1); OSTB(0, 1, 1); OSTB(1, 1, 1);
  OSTB(2, 1, 1); OSTB(3, 1, 1);
  VMW(6); BAR;

#pragma unroll 1
  for (int j = 0; j < 10; ++j) {
    int k0 = j * 3;
    OTILE1(k0 + 0, 0, 2, 6);
    OTILE1(k0 + 1, 1, 0, 6);
    OTILE1(k0 + 2, 2, 1, 6);
  }
  OTILE1(30, 0, 2, 0);   // stages t32 guarded out; VMW(0) confirms tile 31
  OTILE1(31, 1, 0, 0);   // nothing outstanding

#undef OTILE1
#undef OMM
#undef ORD_B2
#undef ORD_A
#undef OSTB
#undef OSTA
#undef VMW
#undef VMW_
#undef BAR
#undef FENCE

#pragma unroll
  for (int nh = 0; nh < 4; ++nh)
#pragma unroll
  for (int mf = 0; mf < 4; ++mf) {
    int n = tn * 256 + nh * 64 + wc * 16 + ln;
    float bz = bias[n];
    int m0 = tm * 128 + wr * 64 + mf * 16 + g * 4;
#pragma unroll
    for (int r = 0; r < 4; ++r)
      outF[(size_t)(m0 + r) * N + n] = acc[nh][mf][r] + bz;
  }
}

// ---------------- causal flash attention (R15-verified: merged halves + dbuf) --
__global__ __launch_bounds__(512) void attn_k(
    const unsigned short* __restrict__ qg, const unsigned short* __restrict__ kg,
    const unsigned short* __restrict__ vtg, unsigned short* __restrict__ ab) {
  __shared__ alignas(16) unsigned short Kl[2][64 * 128];   // [buf][key][hd], swz
  __shared__ alignas(16) unsigned short Vl[2][128 * 64];   // [buf][hd][key], swz
  __shared__ alignas(16) unsigned short Pl[8][16 * 72];    // per wave [qrow][key]
  int bh = (int)blockIdx.x & 31;
  int pr = (int)blockIdx.x >> 5;     // 0..7
  int t = (int)threadIdx.x, l = t & 63, w = t >> 6;
  int g = l >> 4, ln = l & 15;
  int b = bh >> 4, h = bh & 15;
  const size_t bq0 = (size_t)bh * 2048 * 128;

  const int qbA = pr * 128, qbB = (15 - pr) * 128;
  const int qrowA = qbA + w * 16 + ln, qrowB = qbB + w * 16 + ln;
  us8 qfA[4], qfB[4];
#pragma unroll
  for (int kf = 0; kf < 4; ++kf) {
    qfA[kf] = *(const us8*)&qg[bq0 + (size_t)qrowA * 128 + kf * 32 + g * 8];
    qfB[kf] = *(const us8*)&qg[bq0 + (size_t)qrowB * 128 + kf * 32 + g * 8];
  }
  f32x4 oA[8] = {}, oB[8] = {};
  float mA = -1e30f, lA = 0.f, mB = -1e30f, lB = 0.f;
  const int nktA = (qbA >> 6) + 2;   // 2pr+2
  const int nkt  = (qbB >> 6) + 2;   // 32-2pr

#define STAGEKV(kt1, bsel) do {                                               \
    _Pragma("unroll") for (int i = 0; i < 2; ++i) {                           \
      int fb = i * 8192 + w * 1024;                                           \
      int flat = fb + l * 16;                                                 \
      int row = flat >> 8, colb = flat & 255;                                 \
      int sc = colb ^ ((row & 7) << 4);                                       \
      gload16(kg + (bq0 + (size_t)((kt1) * 64 + row) * 128 + (sc >> 1)),      \
              (char*)Kl + (bsel) * 16384 + fb);                               \
      int rv = flat >> 7, cv2 = flat & 127;                                   \
      int scv = cv2 ^ ((rv & 7) << 4);                                        \
      gload16(vtg + (bq0 + (size_t)rv * 2048 + (kt1) * 64 + (scv >> 1)),      \
              (char*)Vl + (bsel) * 16384 + fb);                               \
    }                                                                         \
  } while (0)

#define COMPUTE(qf, o, mrow, lrow, qrow, kt, bo) do {                         \
    f32x4 st[4];                                                              \
    _Pragma("unroll") for (int kfr = 0; kfr < 4; ++kfr) {                     \
      f32x4 acc = {};                                                         \
      int row = kfr * 16 + ln;                                                \
      int swz = (row & 7) << 4;                                               \
      _Pragma("unroll") for (int kf = 0; kf < 4; ++kf) {                      \
        us8 kfrag = *(const us8*)((const char*)Kl + (bo) + row * 256 +        \
                                  ((kf * 64 + g * 16) ^ swz));                \
        acc = MFMA16(kfrag, qf[kf], acc);                                     \
      }                                                                       \
      st[kfr] = acc;                                                          \
    }                                                                         \
    float pmax = -1e30f;                                                      \
    _Pragma("unroll") for (int kfr = 0; kfr < 4; ++kfr)                       \
    _Pragma("unroll") for (int r = 0; r < 4; ++r) {                           \
      int key = (kt) * 64 + kfr * 16 + g * 4 + r;                             \
      float sv = key <= (qrow) ? st[kfr][r] * 0.08838834764831845f : -1e30f;  \
      st[kfr][r] = sv;                                                        \
      pmax = fmaxf(pmax, sv);                                                 \
    }                                                                         \
    pmax = fmaxf(pmax, __shfl_xor(pmax, 16));                                 \
    pmax = fmaxf(pmax, __shfl_xor(pmax, 32));                                 \
    if (__ballot(pmax > (mrow) + 8.f)) {                                      \
      float mnew = pmax > (mrow) + 8.f ? pmax : (mrow);                       \
      float corr = exp2f(((mrow) - mnew) * 1.44269504f);                      \
      (mrow) = mnew;                                                          \
      (lrow) *= corr;                                                         \
      _Pragma("unroll") for (int r = 0; r < 4; ++r) {                         \
        float cr = __shfl(corr, g * 4 + r);                                   \
        _Pragma("unroll") for (int nf = 0; nf < 8; ++nf) o[nf][r] *= cr;      \
      }                                                                       \
    }                                                                         \
    float lsum = 0.f;                                                         \
    _Pragma("unroll") for (int kfr = 0; kfr < 4; ++kfr) {                     \
      us4 pk;                                                                 \
      _Pragma("unroll") for (int r = 0; r < 4; ++r) {                         \
        float p = exp2f((st[kfr][r] - (mrow)) * 1.44269504f);                 \
        lsum += p;                                                            \
        pk[r] = f2bf(p);                                                      \
      }                                                                       \
      *(us4*)&Pl[w][ln * 72 + kfr * 16 + g * 4] = pk;                         \
    }                                                                         \
    lsum += __shfl_xor(lsum, 16);                                             \
    lsum += __shfl_xor(lsum, 32);                                             \
    (lrow) += lsum;                                                           \
    _Pragma("unroll") for (int kf2 = 0; kf2 < 2; ++kf2) {                     \
      us8 pa = *(const us8*)&Pl[w][ln * 72 + kf2 * 32 + g * 8];               \
      _Pragma("unroll") for (int nf = 0; nf < 8; ++nf) {                      \
        int row = nf * 16 + ln;                                               \
        us8 vb = *(const us8*)((const char*)Vl + (bo) + row * 128 +           \
                               ((kf2 * 64 + g * 16) ^ ((row & 7) << 4)));     \
        o[nf] = MFMA16(pa, vb, o[nf]);                                        \
      }                                                                       \
    }                                                                         \
  } while (0)

  STAGEKV(0, 0);
#pragma unroll 1
  for (int kt = 0; kt < nkt; ++kt) {
    __syncthreads();
    if (kt + 1 < nkt) STAGEKV(kt + 1, (kt + 1) & 1);
    int bo = (kt & 1) * 16384;
    COMPUTE(qfB, oB, mB, lB, qrowB, kt, bo);
    if (kt < nktA) COMPUTE(qfA, oA, mA, lA, qrowA, kt, bo);
  }
#undef COMPUTE
#undef STAGEKV

  {
    float invl = 1.f / lB;
#pragma unroll
    for (int r = 0; r < 4; ++r) {
      float ir = __shfl(invl, g * 4 + r);
      int srow = qbB + w * 16 + g * 4 + r;
      size_t base = ((size_t)b * 2048 + srow) * 2048 + h * 128 + ln;
#pragma unroll
      for (int nf = 0; nf < 8; ++nf) ab[base + (size_t)nf * 16] = f2bf(oB[nf][r] * ir);
    }
  }
  {
    float invl = 1.f / lA;
#pragma unroll
    for (int r = 0; r < 4; ++r) {
      float ir = __shfl(invl, g * 4 + r);
      int srow = qbA + w * 16 + g * 4 + r;
      size_t base = ((size_t)b * 2048 + srow) * 2048 + h * 128 + ln;
#pragma unroll
      for (int nf = 0; nf < 8; ++nf) ab[base + (size_t)nf * 16] = f2bf(oA[nf][r] * ir);
    }
  }
}

extern "C" void kernel_launch(void* const* d_in, const int* in_sizes, int n_in,
                              void* d_out, int out_size, void* d_ws, size_t ws_size,
                              hipStream_t stream) {
  const float* x  = (const float*)d_in[0];
  const float* Wq = (const float*)d_in[1];
  const float* bq = (const float*)d_in[2];
  const float* Wk = (const float*)d_in[3];
  const float* Wv = (const float*)d_in[4];
  const float* bv = (const float*)d_in[5];
  const float* Wo = (const float*)d_in[6];
  const float* bo = (const float*)d_in[7];
  float* out = (float*)d_out;

  unsigned short* ws = (unsigned short*)d_ws;
  unsigned short* xb   = ws;                // 8388608 elems (x bf16; later reused as attn out)
  unsigned short* wcat = xb + 8388608;      // 12582912 (Wq|Wk|Wv rows, [6144][2048])
  unsigned short* wob  = wcat + 12582912;   // 4194304
  unsigned short* qb   = wob + 4194304;     // 8388608  [32][2048][128]
  unsigned short* kb   = qb + 8388608;      // 8388608
  unsigned short* vtb  = kb + 8388608;      // 8388608  [32][128][2048] (transposed)
  float2* tab = (float2*)(vtb + 8388608);   // 131072 float2 (1MB) RoPE table

  convert_all<<<2112, 256, 0, stream>>>(x, Wq, Wk, Wv, Wo, xb, wcat, wob, tab);
  gemmsw<0><<<512, 512, 0, stream>>>(xb, wcat, 32, 6144,
                                     nullptr, nullptr, qb, kb, vtb, bq, bv, tab);
  attn_k<<<256, 512, 0, stream>>>(qb, kb, vtb, xb /* a_buf alias */);
  gemmo<<<256, 512, 0, stream>>>(xb, wob, 8, 2048, out, bo);
}